// Round 15
// baseline (30.097 us; speedup 1.0000x reference)
//
#include <hip/hip_runtime.h>

// CfdInterpolateMeshToGrid: B=8, M=8192 mesh pts/batch, G=2048 grid pts/batch,
// D=2, C=64, K=3.  out[g,c] = sum_k w_k * x[nn_k(g), c] / sum_k w_k,
// w_k = 1 / max(d2_k, 1e-16), d2 = (g2 + m2) - 2*dot.
//
// NUMERICS (locked by rounds 1-5 — DO NOT CHANGE):
//   #pragma clang fp contract(off), plus exactly:
//     m2  = (mx*mx) + (my*my)           // unfused (precomputed in scatter)
//     g2  = (gx*gx) + (gy*gy)           // unfused
//     p0  = gx*mx; dot = fmaf(gy,my,p0) // fma-ascending k-contraction (BLAS)
//     t   = g2 + m2
//     d2  = fmaf(-2, dot, t)            // == t - (2*dot) bit-exactly
//   Selection = 3 lex-smallest (d2, idx) — identical to stable top_k and
//   visit-order independent (safe with nondeterministic scatter order).
//
// SCHEDULE (round 15): r14 search ran at 8 waves/CU (512 blocks) — the
// proven-too-low TLP regime (r8/r9: ~45% busy). Now 16 LANES PER POINT:
// 1024 blocks = 4096 waves = 16 waves/CU (r6's 88%-busy regime); ring scan
// ~4.5 cands/lane (256B coalesced per group), 4-level shuffle merge, gather
// 4 points/wave fully unrolled. Binning un-fused to the r11-style parallel
// chain (zero/hist/scan/scatter, 64-8-64 blocks, global atomics) — same
// measured cost as fused but runs on 64 CUs instead of 8.

#define BLK 256
#define LPG 16           // lanes per grid point
#define PPB 16           // grid points per search block (256/LPG)
#define NTB 1024
#define NB 32
#define NBINS (NB * NB)
#define PADIDX 0x7FFFFFFF
#define MARGIN 1e-4f

__global__ void bin_zero(int* __restrict__ hist) {
    hist[blockIdx.x * NTB + threadIdx.x] = 0;
}

__global__ void bin_hist(const float* __restrict__ mesh_pos,
                         int* __restrict__ hist, int M) {
    const int n = blockIdx.x * NTB + threadIdx.x;
    const float2 p = ((const float2*)mesh_pos)[n];
    const int b = n / M;
    const int bx = max(0, min((int)(p.x * (float)NB), NB - 1));
    const int by = max(0, min((int)(p.y * (float)NB), NB - 1));
    atomicAdd(&hist[b * NBINS + by * NB + bx], 1);
}

// One block (1024 thr) per batch: exclusive scan -> starts, cursor.
__global__ void bin_scan(const int* __restrict__ hist,
                         int* __restrict__ starts,   // [B][NBINS+1]
                         int* __restrict__ cursor)   // [B][NBINS]
{
    const int b = blockIdx.x, t = threadIdx.x;
    const int v = hist[b * NBINS + t];
    int sc = v;                                    // wave-inclusive scan
    #pragma unroll
    for (int off = 1; off < 64; off <<= 1) {
        int nv = __shfl_up(sc, off, 64);
        if ((t & 63) >= off) sc += nv;
    }
    __shared__ int wsum[16];
    __shared__ int woff[17];
    if ((t & 63) == 63) wsum[t >> 6] = sc;
    __syncthreads();
    if (t == 0) {
        int acc = 0;
        #pragma unroll
        for (int i = 0; i < 16; ++i) { woff[i] = acc; acc += wsum[i]; }
        woff[16] = acc;
    }
    __syncthreads();
    const int excl = woff[t >> 6] + sc - v;
    starts[b * (NBINS + 1) + t] = excl;
    cursor[b * NBINS + t] = excl;
    if (t == 0) starts[b * (NBINS + 1) + NBINS] = woff[16];   // = M
}

__global__ void bin_scatter(const float* __restrict__ mesh_pos,
                            int* __restrict__ cursor,
                            float4* __restrict__ sxyi,   // (x, y, m2, idx)
                            int M) {
#pragma clang fp contract(off)
    const int n = blockIdx.x * NTB + threadIdx.x;
    const float2 p = ((const float2*)mesh_pos)[n];
    const int b = n / M;
    const int bx = max(0, min((int)(p.x * (float)NB), NB - 1));
    const int by = max(0, min((int)(p.y * (float)NB), NB - 1));
    const float m2 = (p.x * p.x) + (p.y * p.y);   // unfused (contract off)
    const int pos = atomicAdd(&cursor[b * NBINS + by * NB + bx], 1);
    sxyi[(size_t)b * M + pos] =
        make_float4(p.x, p.y, m2, __int_as_float(n - b * M));
}

// lex-(d2, idx) sorted-3 insert; visit-order independent == stable top_k.
#define LEX_INSERT(d2, idx)                                                  \
    if ((d2) < t2 || ((d2) == t2 && (idx) < i2)) {                           \
        if ((d2) < t1 || ((d2) == t1 && (idx) < i1)) {                       \
            t2 = t1; i2 = i1;                                                \
            if ((d2) < t0 || ((d2) == t0 && (idx) < i0)) {                   \
                t1 = t0; i1 = i0; t0 = (d2); i0 = (idx);                     \
            } else { t1 = (d2); i1 = (idx); }                                \
        } else { t2 = (d2); i2 = (idx); }                                    \
    }

// Search: block = 16 grid points, 16 lanes each. 1024 blocks.
__global__ void knn_search(const float* __restrict__ x,
                           const float* __restrict__ grid_pos,
                           const float4* __restrict__ sxyi,
                           const int* __restrict__ starts,
                           float* __restrict__ out,
                           int M, int G)
{
#pragma clang fp contract(off)
    __shared__ float swd0[PPB], swd1[PPB], swd2[PPB];
    __shared__ int   swi0[PPB], swi1[PPB], swi2[PPB];

    const int tid  = threadIdx.x;
    const int g0   = blockIdx.x * PPB;
    const int b    = g0 / G;              // uniform: PPB divides G
    const int pt   = tid >> 4;            // block-local point 0..15
    const int li   = tid & (LPG - 1);     // lane within point group
    const int lane = tid & 63;

    const int g = g0 + pt;
    const float2 gp = ((const float2*)grid_pos)[g];   // broadcast in group
    const float gx = gp.x, gy = gp.y;
    const float g2 = (gx * gx) + (gy * gy);           // unfused

    const int gbx = max(0, min((int)(gx * (float)NB), NB - 1));
    const int gby = max(0, min((int)(gy * (float)NB), NB - 1));
    const int bxlo = max(gbx - 1, 0), bxhi = min(gbx + 1, NB - 1);
    const int bylo = max(gby - 1, 0), byhi = min(gby + 1, NB - 1);

    const int* st = starts + b * (NBINS + 1);          // L2-resident (4KB)
    const float4* bxyi = sxyi + (size_t)b * M;

    float t0 = 1e30f, t1 = 1e30f, t2 = 1e30f;
    int   i0 = PADIDX, i1 = PADIDX, i2 = PADIDX;

    for (int ry = bylo; ry <= byhi; ++ry) {
        const int lo = st[ry * NB + bxlo];
        const int hi = st[ry * NB + bxhi + 1];
        for (int sp = lo + li; sp < hi; sp += LPG) {   // coalesced 256B/group
            const float4 v = bxyi[sp];
            const float p0  = gx * v.x;
            const float dot = fmaf(gy, v.y, p0);
            const float t   = g2 + v.z;                // v.z = m2 (bit-exact)
            const float d2  = fmaf(-2.0f, dot, t);
            const int   idx = __float_as_int(v.w);
            LEX_INSERT(d2, idx)
        }
    }

    // 16-lane lex extract-pop x3. idx uniqueness -> exactly one pop/round.
    float wd2last = 1e30f;
    #pragma unroll
    for (int r = 0; r < 3; ++r) {
        float rd = t0; int ri = i0;
        #pragma unroll
        for (int off = 1; off < LPG; off <<= 1) {
            float od = __shfl_xor(rd, off, 64);
            int   oi = __shfl_xor(ri, off, 64);
            if (od < rd || (od == rd && oi < ri)) { rd = od; ri = oi; }
        }
        if (li == 0) {
            if (r == 0)      { swd0[pt] = rd; swi0[pt] = ri; }
            else if (r == 1) { swd1[pt] = rd; swi1[pt] = ri; }
            else             { swd2[pt] = rd; swi2[pt] = ri; }
        }
        wd2last = rd;
        if (t0 == rd && i0 == ri) {
            t0 = t1; i0 = i1; t1 = t2; i1 = i2; t2 = 1e30f; i2 = PADIDX;
        }
    }

    // Containment check (group-uniform): distance to unexamined region.
    const float w = 1.0f / (float)NB;
    const float dl = (bxlo > 0)      ? (gx - (float)bxlo * w)       : 1e30f;
    const float dr = (bxhi < NB - 1) ? ((float)(bxhi + 1) * w - gx) : 1e30f;
    const float dn = (bylo > 0)      ? (gy - (float)bylo * w)       : 1e30f;
    const float dt = (byhi < NB - 1) ? ((float)(byhi + 1) * w - gy) : 1e30f;
    const float bdd = fminf(fminf(dl, dr), fminf(dn, dt));
    const float bd2 = bdd * bdd;
    const bool need = (li == 0) && !(wd2last + MARGIN < bd2);

    // ---- rare fallback: wave-cooperative exact full-batch scan ---------
    unsigned long long mask = __ballot(need);
    while (mask) {
        const int l = __builtin_ctzll(mask); mask &= mask - 1;
        const int ptf = ((tid & ~63) + l) >> 4;        // block-local point
        const float2 fgp = ((const float2*)grid_pos)[g0 + ptf];
        const float fgx = fgp.x, fgy = fgp.y;
        const float fg2 = (fgx * fgx) + (fgy * fgy);   // unfused
        float t0 = 1e30f, t1 = 1e30f, t2 = 1e30f;
        int   i0 = PADIDX, i1 = PADIDX, i2 = PADIDX;
        for (int j = lane; j < M; j += 64) {
            const float4 v = bxyi[j];
            const float p0  = fgx * v.x;
            const float dot = fmaf(fgy, v.y, p0);
            const float t   = fg2 + v.z;
            const float d2  = fmaf(-2.0f, dot, t);
            const int   idx = __float_as_int(v.w);
            LEX_INSERT(d2, idx)
        }
        #pragma unroll
        for (int r = 0; r < 3; ++r) {                  // 64-lane butterfly
            float rd = t0; int ri = i0;
            #pragma unroll
            for (int off = 32; off; off >>= 1) {
                float od = __shfl_xor(rd, off, 64);
                int   oi = __shfl_xor(ri, off, 64);
                if (od < rd || (od == rd && oi < ri)) { rd = od; ri = oi; }
            }
            if (lane == 0) {
                if (r == 0)      { swd0[ptf] = rd; swi0[ptf] = ri; }
                else if (r == 1) { swd1[ptf] = rd; swi1[ptf] = ri; }
                else             { swd2[ptf] = rd; swi2[ptf] = ri; }
            }
            if (t0 == rd && i0 == ri) {
                t0 = t1; i0 = i1; t1 = t2; i1 = i2; t2 = 1e30f; i2 = PADIDX;
            }
        }
    }
    __syncthreads();

    // ---- gather: wave handles 4 points, lane = channel, full unroll -----
    const int wv = tid >> 6;
    const size_t rowBase = (size_t)b * M * 64;
    #pragma unroll
    for (int q = 0; q < 4; ++q) {
        const int ptq = (wv << 2) + q;
        const float w0 = 1.0f / fmaxf(swd0[ptq], 1e-16f);
        const float w1 = 1.0f / fmaxf(swd1[ptq], 1e-16f);
        const float w2 = 1.0f / fmaxf(swd2[ptq], 1e-16f);
        const int   j0 = swi0[ptq];
        const int   j1 = swi1[ptq];
        const int   j2 = swi2[ptq];
        const float x0 = x[rowBase + (size_t)j0 * 64 + lane];
        const float x1 = x[rowBase + (size_t)j1 * 64 + lane];
        const float x2 = x[rowBase + (size_t)j2 * 64 + lane];
        const float num = ((w0 * x0) + (w1 * x1)) + (w2 * x2);  // unfused
        const float den = (w0 + w1) + w2;
        out[(size_t)(g0 + ptq) * 64 + lane] = num / den;
    }
}

extern "C" void kernel_launch(void* const* d_in, const int* in_sizes, int n_in,
                              void* d_out, int out_size, void* d_ws, size_t ws_size,
                              hipStream_t stream) {
    const float* x        = (const float*)d_in[0];
    const float* mesh_pos = (const float*)d_in[1];
    const float* grid_pos = (const float*)d_in[2];
    // d_in[3] = batch_idx (int64) — contiguous repeat layout, unused.

    const int N  = in_sizes[1] / 2;   // 65536
    const int Gt = in_sizes[2] / 2;   // 16384
    const int B  = 8;
    const int M  = N / B;             // 8192
    const int G  = Gt / B;            // 2048

    // Workspace (~1.2 MB): hist, starts, cursor, packed candidates.
    char* p = (char*)d_ws;
    int*    hist   = (int*)p;     p += (size_t)B * NBINS * sizeof(int);
    int*    starts = (int*)p;     p += (size_t)B * (NBINS + 1) * sizeof(int);
    int*    cursor = (int*)p;     p += (size_t)B * NBINS * sizeof(int);
    float4* sxyi   = (float4*)p;

    bin_zero   <<<(B * NBINS) / NTB, NTB, 0, stream>>>(hist);
    bin_hist   <<<N / NTB, NTB, 0, stream>>>(mesh_pos, hist, M);
    bin_scan   <<<B, NTB, 0, stream>>>(hist, starts, cursor);
    bin_scatter<<<N / NTB, NTB, 0, stream>>>(mesh_pos, cursor, sxyi, M);
    knn_search <<<Gt / PPB, BLK, 0, stream>>>(x, grid_pos, sxyi, starts,
                                              (float*)d_out, M, G);
}

// Round 16
// 24.690 us; speedup vs baseline: 1.2190x; 1.2190x over previous
//
#include <hip/hip_runtime.h>

// CfdInterpolateMeshToGrid: B=8, M=8192 mesh pts/batch, G=2048 grid pts/batch,
// D=2, C=64, K=3.  out[g,c] = sum_k w_k * x[nn_k(g), c] / sum_k w_k,
// w_k = 1 / max(d2_k, 1e-16), d2 = (g2 + m2) - 2*dot.
//
// NUMERICS (locked by rounds 1-5 — DO NOT CHANGE):
//   #pragma clang fp contract(off), plus exactly:
//     m2  = (mx*mx) + (my*my)           // unfused (recomputed at write-out,
//                                       //  same expression -> same bits)
//     g2  = (gx*gx) + (gy*gy)           // unfused
//     p0  = gx*mx; dot = fmaf(gy,my,p0) // fma-ascending k-contraction (BLAS)
//     t   = g2 + m2
//     d2  = fmaf(-2, dot, t)            // == t - (2*dot) bit-exactly
//   Selection = 3 lex-smallest (d2, idx) — identical to stable top_k and
//   visit-order independent (safe with nondeterministic scatter order).
//
// SCHEDULE (round 16): r15 showed LPG=16 loses to LPG=8 (row-tail lane
// waste). Revert to r14 (LPG=8, PPB=32, 512 blocks, fused bin_all) and fix
// its two known costs:
//  (a) knn_search: NO LDS / NO __syncthreads — merge results live in
//      registers (group-uniform after the 8-lane butterfly); gather reads
//      them via __shfl(wd, q*8); fallback delivers via pt==ptf register
//      update (wave-local, no barrier). Row bounds hoisted (6 loads issued
//      before the scan -> L2 latencies overlap).
//  (b) bin_all: counting-sort scatter staged in LDS (float2 pos 64KB +
//      int idx 32KB = 96KB dynamic; 128KB is proven on gfx950), final
//      write-out COALESCED (was 8192 scattered 16B stores/block).

#define BLK 256
#define LPG 8            // lanes per grid point
#define PPB 32           // grid points per search block (BLK/LPG)
#define NTB 1024
#define NB 32
#define NBINS (NB * NB)
#define PADIDX 0x7FFFFFFF
#define MARGIN 1e-4f

// One block per batch: zero + histogram + scan + LDS-staged scatter +
// coalesced write-out of packed candidates (x, y, m2, idx_bits).
__global__ void bin_all(const float* __restrict__ mesh_pos,
                        int* __restrict__ starts,    // [B][NBINS+1]
                        float4* __restrict__ sxyi,
                        int M)
{
#pragma clang fp contract(off)
    __shared__ int h[NBINS];          // histogram, then cursor
    __shared__ int wsum[16];
    __shared__ int woff[17];
    extern __shared__ char dsm[];     // M*12 bytes: staged sorted array
    float2* stage = (float2*)dsm;
    int*    sidl  = (int*)(dsm + (size_t)M * sizeof(float2));

    const int b = blockIdx.x, t = threadIdx.x;

    h[t] = 0;                         // NBINS == NTB == 1024
    __syncthreads();

    const float2* mp = (const float2*)mesh_pos + (size_t)b * M;
    for (int n = t; n < M; n += NTB) {
        const float2 p = mp[n];
        const int bx = max(0, min((int)(p.x * (float)NB), NB - 1));
        const int by = max(0, min((int)(p.y * (float)NB), NB - 1));
        atomicAdd(&h[by * NB + bx], 1);
    }
    __syncthreads();

    const int v = h[t];
    int sc = v;                       // wave-inclusive scan
    #pragma unroll
    for (int off = 1; off < 64; off <<= 1) {
        int nv = __shfl_up(sc, off, 64);
        if ((t & 63) >= off) sc += nv;
    }
    if ((t & 63) == 63) wsum[t >> 6] = sc;
    __syncthreads();
    if (t == 0) {
        int acc = 0;
        #pragma unroll
        for (int i = 0; i < 16; ++i) { woff[i] = acc; acc += wsum[i]; }
        woff[16] = acc;
    }
    __syncthreads();
    const int excl = woff[t >> 6] + sc - v;
    starts[b * (NBINS + 1) + t] = excl;
    if (t == 0) starts[b * (NBINS + 1) + NBINS] = woff[16];   // = M
    __syncthreads();                  // everyone done reading h[t]
    h[t] = excl;                      // cursor
    __syncthreads();

    for (int n = t; n < M; n += NTB) {
        const float2 p = mp[n];       // L1 hit (just streamed)
        const int bx = max(0, min((int)(p.x * (float)NB), NB - 1));
        const int by = max(0, min((int)(p.y * (float)NB), NB - 1));
        const int pos = atomicAdd(&h[by * NB + bx], 1);
        stage[pos] = p;               // LDS scatter (cheap)
        sidl[pos]  = n;               // batch-local index
    }
    __syncthreads();

    // Coalesced write-out; m2 recomputed with the locked unfused expression.
    for (int n = t; n < M; n += NTB) {
        const float2 p = stage[n];
        const float m2 = (p.x * p.x) + (p.y * p.y);   // unfused (contract off)
        sxyi[(size_t)b * M + n] =
            make_float4(p.x, p.y, m2, __int_as_float(sidl[n]));
    }
}

// lex-(d2, idx) sorted-3 insert; visit-order independent == stable top_k.
#define LEX_INSERT(d2, idx)                                                  \
    if ((d2) < t2 || ((d2) == t2 && (idx) < i2)) {                           \
        if ((d2) < t1 || ((d2) == t1 && (idx) < i1)) {                       \
            t2 = t1; i2 = i1;                                                \
            if ((d2) < t0 || ((d2) == t0 && (idx) < i0)) {                   \
                t1 = t0; i1 = i0; t0 = (d2); i0 = (idx);                     \
            } else { t1 = (d2); i1 = (idx); }                                \
        } else { t2 = (d2); i2 = (idx); }                                    \
    }

#define SCAN_ROW(lo, hi)                                                     \
    for (int sp = (lo) + li; sp < (hi); sp += LPG) {                         \
        const float4 v = bxyi[sp];                                           \
        const float p0  = gx * v.x;                                          \
        const float dot = fmaf(gy, v.y, p0);                                 \
        const float t   = g2 + v.z;                                          \
        const float d2  = fmaf(-2.0f, dot, t);                               \
        const int   idx = __float_as_int(v.w);                               \
        LEX_INSERT(d2, idx)                                                  \
    }

// Search: block = 32 grid points, 8 lanes each; 512 blocks. No LDS, no
// barriers — results live in registers, gather reads them via shuffles.
__global__ void knn_search(const float* __restrict__ x,
                           const float* __restrict__ grid_pos,
                           const float4* __restrict__ sxyi,
                           const int* __restrict__ starts,
                           float* __restrict__ out,
                           int M, int G)
{
#pragma clang fp contract(off)
    const int tid  = threadIdx.x;
    const int g0   = blockIdx.x * PPB;
    const int b    = g0 / G;              // uniform: PPB divides G
    const int pt   = tid >> 3;            // block-local point 0..31
    const int li   = tid & 7;             // lane within point group
    const int lane = tid & 63;

    const int g = g0 + pt;
    const float2 gp = ((const float2*)grid_pos)[g];   // broadcast in group
    const float gx = gp.x, gy = gp.y;
    const float g2 = (gx * gx) + (gy * gy);           // unfused

    const int gbx = max(0, min((int)(gx * (float)NB), NB - 1));
    const int gby = max(0, min((int)(gy * (float)NB), NB - 1));
    const int bxlo = max(gbx - 1, 0), bxhi = min(gbx + 1, NB - 1);
    const int bylo = max(gby - 1, 0), byhi = min(gby + 1, NB - 1);

    const int* st = starts + b * (NBINS + 1);          // L2-resident (4KB)
    const float4* bxyi = sxyi + (size_t)b * M;

    // Hoist all row bounds: issue the 6 loads before any scanning.
    const int lo0 = st[bylo * NB + bxlo];
    const int hi0 = st[bylo * NB + bxhi + 1];
    int lo1 = 0, hi1 = 0, lo2 = 0, hi2 = 0;
    if (bylo + 1 <= byhi) { lo1 = st[(bylo + 1) * NB + bxlo];
                            hi1 = st[(bylo + 1) * NB + bxhi + 1]; }
    if (bylo + 2 <= byhi) { lo2 = st[(bylo + 2) * NB + bxlo];
                            hi2 = st[(bylo + 2) * NB + bxhi + 1]; }

    float t0 = 1e30f, t1 = 1e30f, t2 = 1e30f;
    int   i0 = PADIDX, i1 = PADIDX, i2 = PADIDX;

    SCAN_ROW(lo0, hi0)
    SCAN_ROW(lo1, hi1)
    SCAN_ROW(lo2, hi2)

    // 8-lane lex extract-pop x3 -> registers (group-uniform after butterfly).
    float wd0, wd1, wd2; int wi0, wi1, wi2;
    #pragma unroll
    for (int r = 0; r < 3; ++r) {
        float rd = t0; int ri = i0;
        #pragma unroll
        for (int off = 1; off < LPG; off <<= 1) {
            float od = __shfl_xor(rd, off, 64);
            int   oi = __shfl_xor(ri, off, 64);
            if (od < rd || (od == rd && oi < ri)) { rd = od; ri = oi; }
        }
        if (r == 0)      { wd0 = rd; wi0 = ri; }
        else if (r == 1) { wd1 = rd; wi1 = ri; }
        else             { wd2 = rd; wi2 = ri; }
        if (t0 == rd && i0 == ri) {
            t0 = t1; i0 = i1; t1 = t2; i1 = i2; t2 = 1e30f; i2 = PADIDX;
        }
    }

    // Containment check (group-uniform): distance to unexamined region.
    const float w = 1.0f / (float)NB;
    const float dl = (bxlo > 0)      ? (gx - (float)bxlo * w)       : 1e30f;
    const float dr = (bxhi < NB - 1) ? ((float)(bxhi + 1) * w - gx) : 1e30f;
    const float dn = (bylo > 0)      ? (gy - (float)bylo * w)       : 1e30f;
    const float dt = (byhi < NB - 1) ? ((float)(byhi + 1) * w - gy) : 1e30f;
    const float bdd = fminf(fminf(dl, dr), fminf(dn, dt));
    const float bd2 = bdd * bdd;
    const bool need = (li == 0) && !(wd2 + MARGIN < bd2);

    // Rare fallback: wave-cooperative exact scan; deliver via registers.
    unsigned long long mask = __ballot(need);
    while (mask) {
        const int l = __builtin_ctzll(mask); mask &= mask - 1;
        const int ptf = ((tid & ~63) + l) >> 3;        // block-local point
        const float2 fgp = ((const float2*)grid_pos)[g0 + ptf];
        const float fgx = fgp.x, fgy = fgp.y;
        const float fg2 = (fgx * fgx) + (fgy * fgy);   // unfused
        float t0 = 1e30f, t1 = 1e30f, t2 = 1e30f;
        int   i0 = PADIDX, i1 = PADIDX, i2 = PADIDX;
        for (int j = lane; j < M; j += 64) {
            const float4 v = bxyi[j];
            const float p0  = fgx * v.x;
            const float dot = fmaf(fgy, v.y, p0);
            const float t   = fg2 + v.z;
            const float d2  = fmaf(-2.0f, dot, t);
            const int   idx = __float_as_int(v.w);
            LEX_INSERT(d2, idx)
        }
        #pragma unroll
        for (int r = 0; r < 3; ++r) {                  // 64-lane butterfly
            float rd = t0; int ri = i0;
            #pragma unroll
            for (int off = 32; off; off >>= 1) {
                float od = __shfl_xor(rd, off, 64);
                int   oi = __shfl_xor(ri, off, 64);
                if (od < rd || (od == rd && oi < ri)) { rd = od; ri = oi; }
            }
            if (pt == ptf) {                           // owning group only
                if (r == 0)      { wd0 = rd; wi0 = ri; }
                else if (r == 1) { wd1 = rd; wi1 = ri; }
                else             { wd2 = rd; wi2 = ri; }
            }
            if (t0 == rd && i0 == ri) {
                t0 = t1; i0 = i1; t1 = t2; i1 = i2; t2 = 1e30f; i2 = PADIDX;
            }
        }
    }

    // Gather: wave handles its own 8 points; results via shuffle broadcast.
    const int wv = tid >> 6;
    const size_t rowBase = (size_t)b * M * 64;
    #pragma unroll
    for (int q = 0; q < 8; ++q) {
        const int src = q << 3;                        // lane q*8 of this wave
        const float a0 = __shfl(wd0, src, 64);
        const float a1 = __shfl(wd1, src, 64);
        const float a2 = __shfl(wd2, src, 64);
        const int   J0 = __shfl(wi0, src, 64);
        const int   J1 = __shfl(wi1, src, 64);
        const int   J2 = __shfl(wi2, src, 64);
        const float W0 = 1.0f / fmaxf(a0, 1e-16f);
        const float W1 = 1.0f / fmaxf(a1, 1e-16f);
        const float W2 = 1.0f / fmaxf(a2, 1e-16f);
        const float x0 = x[rowBase + (size_t)J0 * 64 + lane];
        const float x1 = x[rowBase + (size_t)J1 * 64 + lane];
        const float x2 = x[rowBase + (size_t)J2 * 64 + lane];
        const float num = ((W0 * x0) + (W1 * x1)) + (W2 * x2);  // unfused
        const float den = (W0 + W1) + W2;
        out[(size_t)(g0 + (wv << 3) + q) * 64 + lane] = num / den;
    }
}

extern "C" void kernel_launch(void* const* d_in, const int* in_sizes, int n_in,
                              void* d_out, int out_size, void* d_ws, size_t ws_size,
                              hipStream_t stream) {
    const float* x        = (const float*)d_in[0];
    const float* mesh_pos = (const float*)d_in[1];
    const float* grid_pos = (const float*)d_in[2];
    // d_in[3] = batch_idx (int64) — contiguous repeat layout, unused.

    const int N  = in_sizes[1] / 2;   // 65536
    const int Gt = in_sizes[2] / 2;   // 16384
    const int B  = 8;
    const int M  = N / B;             // 8192
    const int G  = Gt / B;            // 2048

    // Workspace (~1.1 MB): starts + packed candidates.
    char* p = (char*)d_ws;
    int*    starts = (int*)p;     p += (size_t)B * (NBINS + 1) * sizeof(int);
    float4* sxyi   = (float4*)p;

    const size_t dsmBytes = (size_t)M * 12;   // 96 KB staged sort
    bin_all   <<<B, NTB, dsmBytes, stream>>>(mesh_pos, starts, sxyi, M);
    knn_search<<<Gt / PPB, BLK, 0, stream>>>(x, grid_pos, sxyi, starts,
                                             (float*)d_out, M, G);
}